// Round 10
// baseline (325.778 us; speedup 1.0000x reference)
//
#include <hip/hip_runtime.h>

typedef unsigned short u16;
typedef unsigned int u32;
typedef __attribute__((ext_vector_type(8))) short bf16x8;
typedef __attribute__((ext_vector_type(4))) float f32x4;

// round-to-nearest-even f32 -> bf16
__device__ inline u16 f2bf(float x) {
  union { float f; unsigned u; } v; v.f = x;
  unsigned r = v.u + 0x7fffu + ((v.u >> 16) & 1u);
  return (u16)(r >> 16);
}

// pack two f32 -> two bf16 (truncation) in ONE v_perm_b32. elem0=p0, elem1=p1.
__device__ inline u32 packbf2(float p0, float p1) {
  return __builtin_amdgcn_perm(__float_as_uint(p1), __float_as_uint(p0), 0x07060302u);
}

// async global->LDS, 16B per lane. lds dst = wave-uniform base + lane*16.
__device__ inline void gload16(const void* g, void* l) {
  __builtin_amdgcn_global_load_lds(
      (const __attribute__((address_space(1))) unsigned int*)g,
      (__attribute__((address_space(3))) unsigned int*)l,
      16, 0, 0);
}

// one fused f32->bf16 conversion for ALL 7 tensors.
__global__ void cvt_all(const float* __restrict__ q, const float* __restrict__ k,
                        const float* __restrict__ v,
                        const float* __restrict__ wq, const float* __restrict__ wk,
                        const float* __restrict__ wv, const float* __restrict__ wo,
                        u16* __restrict__ ws) {
  const size_t MT4 = (size_t)2 * 1024 * 1024;   // 8M elems / 4
  const int i = blockIdx.x * blockDim.x + threadIdx.x;
  const int t = blockIdx.y;
  float4 vv;
  ushort4 o;
  if (t < 3) {
    const float* src = (t == 0) ? q : (t == 1) ? k : v;
    vv = ((const float4*)src)[i];
    o.x = f2bf(vv.x); o.y = f2bf(vv.y); o.z = f2bf(vv.z); o.w = f2bf(vv.w);
    ((ushort4*)ws)[(size_t)t * MT4 + i] = o;
  } else {
    if (i >= (1 << 20)) return;                 // 4 * 256K float4
    const int w = i >> 18, j = i & 0x3FFFF;
    const float* src = (w == 0) ? wq : (w == 1) ? wk : (w == 2) ? wv : wo;
    vv = ((const float4*)src)[j];
    o.x = f2bf(vv.x); o.y = f2bf(vv.y); o.z = f2bf(vv.z); o.w = f2bf(vv.w);
    ((ushort4*)(ws + 3 * MT4 * 4))[i] = o;
  }
}

// ---------------- fused Q/K/V projection GEMM ----------------
// 512-thread blocks (8 waves x 64x32 subtiles), 3-buffer LDS, prefetch dist 2,
// counted vmcnt(2) + raw barrier. (Round-9 structure — measured win.)
// Round-10 change: MODE-1 (Vt) permutation is now PER-32-BLOCK bit-permute
//   tok(a) = (a&~31) | ((a&4)<<2) | ((a&24)>>1) | (a&3)
// to match flash's in-register P fragments (swapped QK^T): V position
// a = quad*8 + j (within a 32-block) must hold token (j>>2)*16+quad*4+(j&3).
__global__ __launch_bounds__(512, 4) void gemm_qkv(
    const u16* __restrict__ Xq, const u16* __restrict__ Wqb,
    const float* __restrict__ bq_, const float* __restrict__ bk_,
    const float* __restrict__ bv_, u16* __restrict__ Qp)
{
  constexpr int N = 1024, K = 1024, BK = 32, NT = K / BK;
  constexpr size_t MT = (size_t)8192 * 1024, WT = (size_t)1024 * 1024;
  __shared__ __align__(16) u16 As[3][128 * BK];   // 24 KB
  __shared__ __align__(16) u16 Bs[3][128 * BK];   // 24 KB (total 48 KB)
  const int z = blockIdx.z;
  const u16* A = Xq + (size_t)z * MT;
  const u16* W = Wqb + (size_t)z * WT;
  const float* bias = (z == 0) ? bq_ : (z == 1) ? bk_ : bv_;
  u16* Cout = Qp + (size_t)z * MT;
  const bool vm = (z == 2);

  const int tid = threadIdx.x;
  const int wave = tid >> 6, lane = tid & 63;
  const int quad = lane >> 4, l16 = lane & 15;
  const int m0 = blockIdx.x * 128, n0 = blockIdx.y * 128;

  // staging: thread t loads row t>>2, source granule (t&3)^(row&3) (16B units)
  const int srow = tid >> 2;
  const int sg = ((tid & 3) ^ (srow & 3)) * 8;
  const int arowP = vm ? ((srow & ~31) | ((srow & 4) << 2) | ((srow & 24) >> 1) | (srow & 3))
                       : srow;
  const u16* ag = A + (size_t)(m0 + arowP) * K + sg;
  const u16* bg = W + (size_t)(n0 + srow) * K + sg;

  const int wm = (wave >> 2) * 64, wn = (wave & 3) * 32;
  f32x4 acc[4][2] = {};

#define QKV_STAGE(s)                                   \
  do {                                                 \
    gload16(ag, As[s] + wave * 512);                   \
    gload16(bg, Bs[s] + wave * 512);                   \
    ag += BK; bg += BK;                                \
  } while (0)

  QKV_STAGE(0);
  QKV_STAGE(1);

  int cb = 0, sb = 2;   // compute-buffer, stage-buffer (cycle mod 3)
  for (int kt = 0; kt < NT; ++kt) {
    if (kt + 1 < NT) asm volatile("s_waitcnt vmcnt(2)" ::: "memory");
    else             asm volatile("s_waitcnt vmcnt(0)" ::: "memory");
    __builtin_amdgcn_s_barrier();
    __builtin_amdgcn_sched_barrier(0);
    if (kt + 2 < NT) {
      QKV_STAGE(sb);
      sb = (sb == 2) ? 0 : sb + 1;
    }
    const u16* Ac = As[cb];
    const u16* Bc = Bs[cb];
    cb = (cb == 2) ? 0 : cb + 1;
    bf16x8 af[4], bf[2];
#pragma unroll
    for (int mi = 0; mi < 4; ++mi)
      af[mi] = *(const bf16x8*)(Ac + (wm + mi * 16 + l16) * BK + ((quad ^ (l16 & 3)) * 8));
#pragma unroll
    for (int ni = 0; ni < 2; ++ni)
      bf[ni] = *(const bf16x8*)(Bc + (wn + ni * 16 + l16) * BK + ((quad ^ (l16 & 3)) * 8));
#pragma unroll
    for (int mi = 0; mi < 4; ++mi)
#pragma unroll
      for (int ni = 0; ni < 2; ++ni)
        acc[mi][ni] = __builtin_amdgcn_mfma_f32_16x16x32_bf16(af[mi], bf[ni], acc[mi][ni], 0, 0, 0);
  }
#undef QKV_STAGE

#pragma unroll
  for (int ni = 0; ni < 2; ++ni) {
    const int col = n0 + wn + ni * 16 + l16;
    const float bv = bias[col];
#pragma unroll
    for (int mi = 0; mi < 4; ++mi) {
      const int mrow = m0 + wm + mi * 16 + quad * 4;
      f32x4 a = acc[mi][ni];
      if (!vm) {
#pragma unroll
        for (int r = 0; r < 4; ++r)
          Cout[(size_t)(mrow + r) * N + col] = f2bf(a[r] + bv);
      } else {
        const int bq = mrow >> 11, t = mrow & 2047;
        const int h = col >> 6, d = col & 63;
        ushort4 pk;
        pk.x = f2bf(a[0] + bv); pk.y = f2bf(a[1] + bv);
        pk.z = f2bf(a[2] + bv); pk.w = f2bf(a[3] + bv);
        *(ushort4*)(Cout + ((size_t)((bq * 16 + h) * 64 + d)) * 2048 + t) = pk;
      }
    }
  }
}

// ---------------- Wo GEMM (fp32 out), 512-thread structure (round-9) -------
__global__ __launch_bounds__(512, 4) void gemm_wo(
    const u16* __restrict__ A, const u16* __restrict__ W,
    const float* __restrict__ bias, float* __restrict__ Cout)
{
  constexpr int N = 1024, K = 1024, BK = 32, NT = K / BK;
  __shared__ __align__(16) u16 As[3][128 * BK];
  __shared__ __align__(16) u16 Bs[3][128 * BK];
  const int tid = threadIdx.x;
  const int wave = tid >> 6, lane = tid & 63;
  const int quad = lane >> 4, l16 = lane & 15;
  const int m0 = blockIdx.x * 128, n0 = blockIdx.y * 128;

  const int srow = tid >> 2;
  const int sg = ((tid & 3) ^ (srow & 3)) * 8;
  const u16* ag = A + (size_t)(m0 + srow) * K + sg;
  const u16* bg = W + (size_t)(n0 + srow) * K + sg;

  const int wm = (wave >> 2) * 64, wn = (wave & 3) * 32;
  f32x4 acc[4][2] = {};

#define WO_STAGE(s)                                    \
  do {                                                 \
    gload16(ag, As[s] + wave * 512);                   \
    gload16(bg, Bs[s] + wave * 512);                   \
    ag += BK; bg += BK;                                \
  } while (0)

  WO_STAGE(0);
  WO_STAGE(1);

  int cb = 0, sb = 2;
  for (int kt = 0; kt < NT; ++kt) {
    if (kt + 1 < NT) asm volatile("s_waitcnt vmcnt(2)" ::: "memory");
    else             asm volatile("s_waitcnt vmcnt(0)" ::: "memory");
    __builtin_amdgcn_s_barrier();
    __builtin_amdgcn_sched_barrier(0);
    if (kt + 2 < NT) {
      WO_STAGE(sb);
      sb = (sb == 2) ? 0 : sb + 1;
    }
    const u16* Ac = As[cb];
    const u16* Bc = Bs[cb];
    cb = (cb == 2) ? 0 : cb + 1;
    bf16x8 af[4], bf[2];
#pragma unroll
    for (int mi = 0; mi < 4; ++mi)
      af[mi] = *(const bf16x8*)(Ac + (wm + mi * 16 + l16) * BK + ((quad ^ (l16 & 3)) * 8));
#pragma unroll
    for (int ni = 0; ni < 2; ++ni)
      bf[ni] = *(const bf16x8*)(Bc + (wn + ni * 16 + l16) * BK + ((quad ^ (l16 & 3)) * 8));
#pragma unroll
    for (int mi = 0; mi < 4; ++mi)
#pragma unroll
      for (int ni = 0; ni < 2; ++ni)
        acc[mi][ni] = __builtin_amdgcn_mfma_f32_16x16x32_bf16(af[mi], bf[ni], acc[mi][ni], 0, 0, 0);
  }
#undef WO_STAGE

#pragma unroll
  for (int ni = 0; ni < 2; ++ni) {
    const int col = n0 + wn + ni * 16 + l16;
    const float bv = bias[col];
#pragma unroll
    for (int mi = 0; mi < 4; ++mi) {
      const int mrow = m0 + wm + mi * 16 + quad * 4;
      f32x4 a = acc[mi][ni];
#pragma unroll
      for (int r = 0; r < 4; ++r)
        Cout[(size_t)(mrow + r) * N + col] = a[r] + bv;
    }
  }
}

// ---------------- flash attention ----------------
// Round-10 change: SWAPPED QK^T -> P stays entirely in registers; Ps LDS
// buffer and its write/read round-trip are DELETED.
//   - A and B fragments of mfma_16x16x32 have identical per-lane layouts, so
//     mfma(kf, qf) reuses the same registers and yields S^T: lane holds
//     S[q=l16][key = cc*16 + quad*4 + r] in Sg[cc][r].
//   - After exp2, those 16 values pack (packbf2 x8) directly into two bf16x8
//     A-fragments pa[ksl]: slot j of pa[ksl] = key (j>>2)*16 + quad*4 + (j&3)
//     of 32-block ksl. V comes permuted to match (gemm_qkv MODE-1 pi), so PV
//     and lsum consume pa directly. C/D layouts of lsum/PV/epilogue unchanged.
// Removes per wave-kt: 16 ds_writes + 8 ds_reads + the in-path lgkm wait;
// LDS 81920 -> 65536. Staging, swizzles, setprio identical to round 5/7/9
// (measured 80.2 us, 0 conflicts). Spill tripwire = FETCH/WRITE.
__global__ __launch_bounds__(512, 4) void flash_attn(
    const u16* __restrict__ Qp, const u16* __restrict__ Kp,
    const u16* __restrict__ Vt, u16* __restrict__ Ctx)
{
  constexpr int TQ = 2048, DM = 1024, DK = 64;
  __shared__ __align__(16) u16 Ks[2][128 * 64];    // 32768 B
  __shared__ __align__(16) u16 Vts[2][64 * 128];   // 32768 B (total 65536)

  const int bh = blockIdx.x, b = bh >> 4, h = bh & 15;
  const int qt = blockIdx.y;
  const int tid = threadIdx.x, wave = tid >> 6, lane = tid & 63;
  const int quad = lane >> 4, l16 = lane & 15;
  const int q0 = qt * 256 + wave * 32;

  const int C0 = tid, C1 = 512 + tid;
  const int kr0 = C0 >> 3, kr1 = C1 >> 3;
  const u16* kp0 = Kp + (size_t)(b * TQ + kr0) * DM + h * DK + (((C0 & 7) ^ (kr0 & 7)) * 8);
  const u16* kp1 = Kp + (size_t)(b * TQ + kr1) * DM + h * DK + (((C1 & 7) ^ (kr1 & 7)) * 8);
  const int vd0 = C0 >> 4, vd1 = C1 >> 4;
  const u16* vp0 = Vt + (size_t)(bh * DK + vd0) * TQ + (((C0 & 15) ^ (vd0 & 15)) * 8);
  const u16* vp1 = Vt + (size_t)(bh * DK + vd1) * TQ + (((C1 & 15) ^ (vd1 & 15)) * 8);

  bf16x8 qf[2][2];
#pragma unroll
  for (int mi = 0; mi < 2; ++mi)
#pragma unroll
    for (int ks = 0; ks < 2; ++ks)
      qf[mi][ks] = *(const bf16x8*)(Qp + (size_t)(b * TQ + q0 + mi * 16 + l16) * DM
                                       + h * DK + ks * 32 + quad * 8);

  f32x4 O[2][4] = {};
  f32x4 lsum[2] = {};
  const float CS = 0.18033688011112042f;
  const float CB = 0.0028153f;

  bf16x8 onesv;
#pragma unroll
  for (int j = 0; j < 8; ++j) onesv[j] = (short)0x3F80;  // bf16 1.0

  gload16(kp0, &Ks[0][C0 * 8]);
  gload16(kp1, &Ks[0][C1 * 8]);
  gload16(vp0, &Vts[0][C0 * 8]);
  gload16(vp1, &Vts[0][C1 * 8]);
  kp0 += 128 * DM; kp1 += 128 * DM; vp0 += 128; vp1 += 128;
  __syncthreads();

  const int kg = quad ^ (l16 & 7);
  int cur = 0;
  for (int kt = 0; kt < TQ / 128; ++kt) {
    if (kt + 1 < TQ / 128) {
      const int nb = cur ^ 1;
      gload16(kp0, &Ks[nb][C0 * 8]);
      gload16(kp1, &Ks[nb][C1 * 8]);
      gload16(vp0, &Vts[nb][C0 * 8]);
      gload16(vp1, &Vts[nb][C1 * 8]);
      kp0 += 128 * DM; kp1 += 128 * DM; vp0 += 128; vp1 += 128;
    }
    const u16* Kc = Ks[cur];
    const u16* Vc = Vts[cur];

#pragma unroll
    for (int g = 0; g < 2; ++g) {
      // swapped QK^T: Sg[mi][cc][r] = S[q=l16][key = g*64 + cc*16 + quad*4 + r]
      f32x4 Sg[2][4];
      __builtin_amdgcn_s_setprio(1);
#pragma unroll
      for (int cc = 0; cc < 4; ++cc) {
        const int row = (g * 4 + cc) * 16 + l16;
        bf16x8 kf0 = *(const bf16x8*)(Kc + row * 64 + kg * 8);
        bf16x8 kf1 = *(const bf16x8*)(Kc + row * 64 + (kg ^ 4) * 8);
#pragma unroll
        for (int mi = 0; mi < 2; ++mi) {
          f32x4 zz = {};
          zz = __builtin_amdgcn_mfma_f32_16x16x32_bf16(kf0, qf[mi][0], zz, 0, 0, 0);
          Sg[mi][cc] = __builtin_amdgcn_mfma_f32_16x16x32_bf16(kf1, qf[mi][1], zz, 0, 0, 0);
        }
      }
      __builtin_amdgcn_s_setprio(0);
      // exp2 -> pack into in-register A-fragments. pa[mi][ksl] slot j holds
      // P for key (j>>2)*16 + quad*4 + (j&3) of 32-block ksl (matches pi).
      bf16x8 pa[2][2];
#pragma unroll
      for (int mi = 0; mi < 2; ++mi) {
#pragma unroll
        for (int ksl = 0; ksl < 2; ++ksl) {
          uint4 u;
          u.x = packbf2(__builtin_amdgcn_exp2f(fmaf(Sg[mi][2 * ksl][0], CS, CB)),
                        __builtin_amdgcn_exp2f(fmaf(Sg[mi][2 * ksl][1], CS, CB)));
          u.y = packbf2(__builtin_amdgcn_exp2f(fmaf(Sg[mi][2 * ksl][2], CS, CB)),
                        __builtin_amdgcn_exp2f(fmaf(Sg[mi][2 * ksl][3], CS, CB)));
          u.z = packbf2(__builtin_amdgcn_exp2f(fmaf(Sg[mi][2 * ksl + 1][0], CS, CB)),
                        __builtin_amdgcn_exp2f(fmaf(Sg[mi][2 * ksl + 1][1], CS, CB)));
          u.w = packbf2(__builtin_amdgcn_exp2f(fmaf(Sg[mi][2 * ksl + 1][2], CS, CB)),
                        __builtin_amdgcn_exp2f(fmaf(Sg[mi][2 * ksl + 1][3], CS, CB)));
          pa[mi][ksl] = *(const bf16x8*)&u;
        }
        lsum[mi] = __builtin_amdgcn_mfma_f32_16x16x32_bf16(pa[mi][0], onesv, lsum[mi], 0, 0, 0);
        lsum[mi] = __builtin_amdgcn_mfma_f32_16x16x32_bf16(pa[mi][1], onesv, lsum[mi], 0, 0, 0);
      }
      // PV: vf read once, both strips accumulate
      __builtin_amdgcn_s_setprio(1);
#pragma unroll
      for (int ksl = 0; ksl < 2; ++ksl)
#pragma unroll
        for (int ni = 0; ni < 4; ++ni) {
          const int gv = g * 8 + ksl * 4 + quad;
          bf16x8 vf = *(const bf16x8*)(Vc + (ni * 16 + l16) * 128 + ((gv ^ l16) * 8));
          O[0][ni] = __builtin_amdgcn_mfma_f32_16x16x32_bf16(pa[0][ksl], vf, O[0][ni], 0, 0, 0);
          O[1][ni] = __builtin_amdgcn_mfma_f32_16x16x32_bf16(pa[1][ksl], vf, O[1][ni], 0, 0, 0);
        }
      __builtin_amdgcn_s_setprio(0);
    }
    __syncthreads();
    cur ^= 1;
  }

  // epilogue: O /= l, write context [B,T,D] bf16
#pragma unroll
  for (int mi = 0; mi < 2; ++mi)
#pragma unroll
    for (int r = 0; r < 4; ++r) {
      const float inv = 1.0f / lsum[mi][r];
      const int q = q0 + mi * 16 + quad * 4 + r;
#pragma unroll
      for (int ni = 0; ni < 4; ++ni) {
        const int col = h * DK + ni * 16 + l16;
        Ctx[(size_t)(b * TQ + q) * DM + col] = f2bf(O[mi][ni][r] * inv);
      }
    }
}

extern "C" void kernel_launch(void* const* d_in, const int* in_sizes, int n_in,
                              void* d_out, int out_size, void* d_ws, size_t ws_size,
                              hipStream_t stream)
{
  (void)in_sizes; (void)n_in; (void)out_size; (void)ws_size;
  const float* query = (const float*)d_in[0];
  const float* key_  = (const float*)d_in[1];
  const float* value = (const float*)d_in[2];
  const float* Wq = (const float*)d_in[3];
  const float* bq = (const float*)d_in[4];
  const float* Wk = (const float*)d_in[5];
  const float* bk = (const float*)d_in[6];
  const float* Wv = (const float*)d_in[7];
  const float* bv = (const float*)d_in[8];
  const float* Wo = (const float*)d_in[9];
  const float* bo = (const float*)d_in[10];

  const size_t MT = (size_t)4 * 2048 * 1024;  // 8M elements
  const size_t WT = (size_t)1024 * 1024;      // 1M elements
  u16* ws  = (u16*)d_ws;
  u16* Xq  = ws;                 // Xq, Xk, Xv contiguous (stride MT)
  u16* Wqb = Xq + 3 * MT;        // Wqb, Wkb, Wvb, Wob contiguous (stride WT)
  u16* Qp  = Wqb + 4 * WT;       // Qp, Kp, Vt contiguous (stride MT)
  u16* Kp  = Qp + MT;
  u16* Vt  = Kp + MT;
  u16* Ctx = Vt + MT;
  u16* Wob = Wqb + 3 * WT;

  cvt_all<<<dim3(8192, 4), 256, 0, stream>>>(
      query, key_, value, Wq, Wk, Wv, Wo, ws);

  gemm_qkv<<<dim3(64, 8, 3), 512, 0, stream>>>(Xq, Wqb, bq, bk, bv, Qp);

  flash_attn<<<dim3(64, 8), 512, 0, stream>>>(Qp, Kp, Vt, Ctx);

  gemm_wo<<<dim3(64, 8), 512, 0, stream>>>(Ctx, Wob, bo, (float*)d_out);
}